// Round 11
// baseline (25.891 us; speedup 1.0000x reference)
//
#include <hip/hip_runtime.h>

#define BATCH 2048
#define IND   256
#define OUTD  256

typedef __attribute__((ext_vector_type(8))) short bf16x8;
typedef __attribute__((ext_vector_type(4))) float f32x4;

__device__ __forceinline__ ushort f2bf(float f) {
    uint u = __builtin_bit_cast(uint, f);
    u += 0x7fffu + ((u >> 16) & 1u);          // RNE
    return (ushort)(u >> 16);
}
__device__ __forceinline__ uint pack2(float lo, float hi) {
    return (uint)f2bf(lo) | ((uint)f2bf(hi) << 16);
}

// ---------------- ws layout ----------------
#define BIASOFF (1u << 20)                 // W: [0, 1MB); bias after
#define WS_NEED ((size_t)BIASOFF + 4096)

// features for one x value: [silu, B0..B6] (c7 folded: B7 = 1 - sum -> bias)
__device__ __forceinline__ uint4 feat_pack(float xv) {
    const float u = (xv + 1.0f) * 2.5f;
    float cif = floorf(u);
    cif = fminf(fmaxf(cif, 0.0f), 4.0f);
    const int ci = (int)cif;
    const float f = u - cif, mf = 1.0f - f;
    const float f2 = f * f, f3 = f2 * f;
    const float k6 = 1.0f / 6.0f;
    const float w0 = mf * mf * mf * k6;
    const float w1 = (3.0f * f3 - 6.0f * f2 + 4.0f) * k6;
    const float w3 = f3 * k6;
    const float w2 = 1.0f - w0 - w1 - w3;
    const float sg = __fdividef(xv, 1.0f + __expf(-xv));
    const float B0 = (ci == 0) ? w0 : 0.f;
    const float B1 = (ci == 1) ? w0 : (ci == 0) ? w1 : 0.f;
    const float B2 = (ci == 2) ? w0 : (ci == 1) ? w1 : (ci == 0) ? w2 : 0.f;
    const float B3 = (ci == 3) ? w0 : (ci == 2) ? w1 : (ci == 1) ? w2 : (ci == 0) ? w3 : 0.f;
    const float B4 = (ci == 4) ? w0 : (ci == 3) ? w1 : (ci == 2) ? w2 : (ci == 1) ? w3 : 0.f;
    const float B5 = (ci == 4) ? w1 : (ci == 3) ? w2 : (ci == 2) ? w3 : 0.f;
    const float B6 = (ci == 4) ? w2 : (ci == 3) ? w3 : 0.f;
    uint4 v;
    v.x = pack2(sg, B0); v.y = pack2(B1, B2);
    v.z = pack2(B3, B4); v.w = pack2(B5, B6);
    return v;
}

// ============ kernel 1: W + bias only (tiny, proven) ============
__global__ __launch_bounds__(256) void kan_wb(
    const float* __restrict__ coef, const float* __restrict__ sb,
    const float* __restrict__ ss, const float* __restrict__ mask,
    uint4* __restrict__ W, float* __restrict__ bias)
{
    const int bid = blockIdx.x, tid = threadIdx.x;
    __shared__ float part[32][8];
    if (bid < 256) {
        const int io = bid * OUTD + tid;
        const float m = mask[io], b = sb[io], sp = ss[io];
        const float4* cp = reinterpret_cast<const float4*>(coef + (size_t)io * 8);
        const float4 c0 = cp[0], c1 = cp[1];
        const float wb = m * b, wsp = m * sp;
        const float c7 = c1.w;
        uint4 w;
        w.x = pack2(wb,                wsp * (c0.x - c7));
        w.y = pack2(wsp * (c0.y - c7), wsp * (c0.z - c7));
        w.z = pack2(wsp * (c0.w - c7), wsp * (c1.x - c7));
        w.w = pack2(wsp * (c1.y - c7), wsp * (c1.z - c7));
        W[io] = w;
    } else {
        const int o0 = (bid - 256) * 8;
        const int ol = tid & 7, ig = tid >> 3;
        float s = 0.f;
#pragma unroll
        for (int ii = 0; ii < 8; ++ii) {
            const int i = ig * 8 + ii;
            const int io = i * OUTD + o0 + ol;
            s += mask[io] * ss[io] * coef[(size_t)io * 8 + 7];
        }
        part[ig][ol] = s;
        __syncthreads();
        if (tid < 8) {
            float acc = 0.f;
#pragma unroll
            for (int g2 = 0; g2 < 32; ++g2) acc += part[g2][tid];
            bias[o0 + tid] = acc;
        }
    }
}

// ============ kernel 2: fused feature + GEMM, BM=64 (halved W traffic) ============
// 256 blocks x 512 threads. Block tile 64M x 32N. o-tile = bid&7 (XCD-pinned, 128KB
// W-slice), m-tile = bid>>3 (0..31). 8 waves = kq(4-way K-split) x mh(2 M-halves),
// wave tile 32M x 32N = 2x2 frags. Per 32-i chunk: 4 reg-direct B-frags + 4 x-prefetch
// loads at top, 4 feat_packs/thread (hides latency) -> XOR-swizzled At, 4 ds_read_b128,
// 8 MFMA, 2 barriers. Epilogue: 4-way kq-reduce in LDS + bias.
__global__ __launch_bounds__(512, 2) void kan_fgemm(
    const float* __restrict__ x, const uint4* __restrict__ W,
    const float* __restrict__ bias, float* __restrict__ out)
{
    __shared__ float xs2[64 * 32];     // 8 KB current x-chunk
    __shared__ uint4 At[64 * 32];      // 32 KB A-tile, slot ^= row&7

    const int tid  = threadIdx.x;
    const int lane = tid & 63, wid = tid >> 6;
    const int mh = wid & 1, kq = wid >> 1;            // kq 0..3
    const int r = lane & 15, g = lane >> 4;
    const int bid = blockIdx.x;
    const int o0 = (bid & 7) * 32;                    // one n-tile per XCD
    const int b0 = (bid >> 3) * 64;

    const int frow = tid >> 5;        // 0..15 (+16p covers 64 rows)
    const int fil  = tid & 31;

    // ---- prologue: stage x chunk 0 ----
#pragma unroll
    for (int p = 0; p < 4; ++p)
        xs2[(frow + 16 * p) * 32 + fil] = x[(size_t)(b0 + frow + 16 * p) * IND + fil];
    __syncthreads();

    f32x4 acc[2][2] = {};

#pragma unroll
    for (int t = 0; t < 8; ++t) {
        const int i0 = t * 32;

        // ---- B-frag loads (register-direct, XCD-local slice) ----
        const uint4* pB = W + (size_t)(i0 + kq * 8 + g) * OUTD + o0 + r;
        const bf16x8 b00 = *reinterpret_cast<const bf16x8*>(pB);            // ks0,nf0
        const bf16x8 b01 = *reinterpret_cast<const bf16x8*>(pB + 16);       // ks0,nf1
        const bf16x8 b10 = *reinterpret_cast<const bf16x8*>(pB + 4 * OUTD); // ks1,nf0
        const bf16x8 b11 = *reinterpret_cast<const bf16x8*>(pB + 4 * OUTD + 16);

        // ---- x-chunk t+1 prefetch ----
        float xp0 = 0.f, xp1 = 0.f, xp2 = 0.f, xp3 = 0.f;
        if (t < 7) {
            const float* px = x + (size_t)(b0 + frow) * IND + i0 + 32 + fil;
            xp0 = px[0];
            xp1 = px[16 * IND];
            xp2 = px[32 * IND];
            xp3 = px[48 * IND];
        }

        // ---- features for chunk t (hides B/x latency) ----
        const uint4 f0 = feat_pack(xs2[frow * 32 + fil]);
        const uint4 f1 = feat_pack(xs2[(frow + 16) * 32 + fil]);
        const uint4 f2 = feat_pack(xs2[(frow + 32) * 32 + fil]);
        const uint4 f3 = feat_pack(xs2[(frow + 48) * 32 + fil]);

        __syncthreads();              // prev MFMA At-reads + this-chunk xs2 reads done
        At[frow * 32 + (fil ^ (frow & 7))] = f0;
        At[(frow + 16) * 32 + (fil ^ ((frow + 16) & 7))] = f1;
        At[(frow + 32) * 32 + (fil ^ ((frow + 32) & 7))] = f2;
        At[(frow + 48) * 32 + (fil ^ ((frow + 48) & 7))] = f3;
        if (t < 7) {
            xs2[frow * 32 + fil] = xp0;
            xs2[(frow + 16) * 32 + fil] = xp1;
            xs2[(frow + 32) * 32 + fil] = xp2;
            xs2[(frow + 48) * 32 + fil] = xp3;
        }
        __syncthreads();              // At (and next xs2) visible

        // ---- A-frags + MFMA (2 m-frags x 2 k-steps) ----
        const int ar0 = mh * 32 + r, ar1 = ar0 + 16;
        const int s0 = kq * 8 + g, s1 = s0 + 4;
        const bf16x8 a00 = *reinterpret_cast<const bf16x8*>(At + ar0 * 32 + (s0 ^ (ar0 & 7)));
        const bf16x8 a10 = *reinterpret_cast<const bf16x8*>(At + ar1 * 32 + (s0 ^ (ar1 & 7)));
        const bf16x8 a01 = *reinterpret_cast<const bf16x8*>(At + ar0 * 32 + (s1 ^ (ar0 & 7)));
        const bf16x8 a11 = *reinterpret_cast<const bf16x8*>(At + ar1 * 32 + (s1 ^ (ar1 & 7)));

        acc[0][0] = __builtin_amdgcn_mfma_f32_16x16x32_bf16(a00, b00, acc[0][0], 0, 0, 0);
        acc[0][1] = __builtin_amdgcn_mfma_f32_16x16x32_bf16(a00, b01, acc[0][1], 0, 0, 0);
        acc[1][0] = __builtin_amdgcn_mfma_f32_16x16x32_bf16(a10, b00, acc[1][0], 0, 0, 0);
        acc[1][1] = __builtin_amdgcn_mfma_f32_16x16x32_bf16(a10, b01, acc[1][1], 0, 0, 0);
        acc[0][0] = __builtin_amdgcn_mfma_f32_16x16x32_bf16(a01, b10, acc[0][0], 0, 0, 0);
        acc[0][1] = __builtin_amdgcn_mfma_f32_16x16x32_bf16(a01, b11, acc[0][1], 0, 0, 0);
        acc[1][0] = __builtin_amdgcn_mfma_f32_16x16x32_bf16(a11, b10, acc[1][0], 0, 0, 0);
        acc[1][1] = __builtin_amdgcn_mfma_f32_16x16x32_bf16(a11, b11, acc[1][1], 0, 0, 0);
    }

    // ---- epilogue: 4-way kq-reduce per mh (reuse At), add bias, store ----
    __syncthreads();
    float* red = (float*)At;          // 2 x 3 x 1024 floats = 24 KB
    if (kq > 0) {
        float* dst = red + (size_t)(mh * 3 + kq - 1) * 1024;
#pragma unroll
        for (int mf = 0; mf < 2; ++mf)
#pragma unroll
            for (int nf = 0; nf < 2; ++nf)
                *reinterpret_cast<f32x4*>(dst + (mf * 2 + nf) * 256 + lane * 4) = acc[mf][nf];
    }
    __syncthreads();
    if (kq == 0) {
#pragma unroll
        for (int mf = 0; mf < 2; ++mf)
#pragma unroll
            for (int nf = 0; nf < 2; ++nf) {
                f32x4 s = acc[mf][nf];
                const int sl = (mf * 2 + nf) * 256 + lane * 4;
#pragma unroll
                for (int kk = 0; kk < 3; ++kk) {
                    const f32x4 v = *reinterpret_cast<const f32x4*>(
                        red + (size_t)(mh * 3 + kk) * 1024 + sl);
                    s.x += v.x; s.y += v.y; s.z += v.z; s.w += v.w;
                }
                const int col  = o0 + nf * 16 + r;
                const int row0 = b0 + mh * 32 + mf * 16 + g * 4;
                const float bv = bias[col];
#pragma unroll
                for (int e = 0; e < 4; ++e)
                    out[(size_t)(row0 + e) * OUTD + col] = s[e] + bv;
            }
    }
}

// ============ fallback (used only if ws too small) ============
#define KPI  16
#define IPC  8
#define KC   (IPC * KPI)

__global__ __launch_bounds__(256, 2) void kan_mfma(
    const float* __restrict__ x, const float* __restrict__ coef,
    const float* __restrict__ scale_base, const float* __restrict__ scale_sp,
    const float* __restrict__ mask, float* __restrict__ out)
{
    const int tid = threadIdx.x;
    const int b0 = blockIdx.x * 32, o0 = blockIdx.y * 32;
    __shared__ uint Fa[32 * KC / 2];
    __shared__ uint Wt2[32 * KC / 2];
    for (int j = tid; j < 32 * KC / 2; j += 256) { Fa[j] = 0u; Wt2[j] = 0u; }
    const int lane = tid & 63, wid = tid >> 6;
    const int wmv = (wid >> 1) * 16, wnv = (wid & 1) * 16;
    f32x4 acc = {0.f, 0.f, 0.f, 0.f};
    const int fb = tid & 31, il = tid >> 5;
    for (int ic = 0; ic < IND / IPC; ++ic) {
        const int i = ic * IPC + il;
        __syncthreads();
        {
            const uint4 fp = feat_pack(x[(b0 + fb) * IND + i]);
            const int base = fb * (KC / 2) + il * (KPI / 2);
            const int sw = (fb & 7) << 2;
            Fa[(base + 0) ^ sw] = fp.x; Fa[(base + 1) ^ sw] = fp.y;
            Fa[(base + 2) ^ sw] = fp.z; Fa[(base + 3) ^ sw] = fp.w;
            ((ushort*)Fa)[2 * ((base + 4) ^ sw)] = 0;
        }
        {
            const int io = i * OUTD + o0 + fb;
            const float m = mask[io];
            const float wb = scale_base[io] * m, wsv = scale_sp[io] * m;
            const float4* cp = reinterpret_cast<const float4*>(coef + (size_t)io * 8);
            const float4 c0 = cp[0], c1 = cp[1];
            const float c7 = c1.w;
            const int base = fb * (KC / 2) + il * (KPI / 2);
            const int sw = (fb & 7) << 2;
            Wt2[(base + 0) ^ sw] = pack2(wb, wsv * (c0.x - c7));
            Wt2[(base + 1) ^ sw] = pack2(wsv * (c0.y - c7), wsv * (c0.z - c7));
            Wt2[(base + 2) ^ sw] = pack2(wsv * (c0.w - c7), wsv * (c1.x - c7));
            Wt2[(base + 3) ^ sw] = pack2(wsv * (c1.y - c7), wsv * (c1.z - c7));
            ((ushort*)Wt2)[2 * ((base + 4) ^ sw)] = 0;
        }
        __syncthreads();
        {
            const ushort* fs = (const ushort*)Fa;
            const ushort* wsd = (const ushort*)Wt2;
            const int ar = wmv + (lane & 15), br = wnv + (lane & 15);
            const int kg = (lane >> 4) * 8;
#pragma unroll
            for (int ksi = 0; ksi < 4; ++ksi) {
                const int ka = ksi * 32 + kg;
                const int ia = (ar * KC + ka) ^ ((ar & 7) << 3);
                const int ib = (br * KC + ka) ^ ((br & 7) << 3);
                bf16x8 a = *reinterpret_cast<const bf16x8*>(fs + ia);
                bf16x8 b = *reinterpret_cast<const bf16x8*>(wsd + ib);
                acc = __builtin_amdgcn_mfma_f32_16x16x32_bf16(a, b, acc, 0, 0, 0);
            }
        }
    }
    const int col = o0 + wnv + (lane & 15);
    const int row0 = b0 + wmv + ((lane >> 4) << 2);
    float bv = 0.f;
    for (int i = 0; i < IND; ++i) {
        const int io = i * OUTD + col;
        bv += mask[io] * scale_sp[io] * coef[(size_t)io * 8 + 7];
    }
#pragma unroll
    for (int rr = 0; rr < 4; ++rr)
        out[(size_t)(row0 + rr) * OUTD + col] = acc[rr] + bv;
}

extern "C" void kernel_launch(void* const* d_in, const int* in_sizes, int n_in,
                              void* d_out, int out_size, void* d_ws, size_t ws_size,
                              hipStream_t stream) {
    const float* x          = (const float*)d_in[0];
    const float* coef       = (const float*)d_in[2];
    const float* scale_base = (const float*)d_in[3];
    const float* scale_sp   = (const float*)d_in[4];
    const float* mask       = (const float*)d_in[5];
    float* out = (float*)d_out;

    if (ws_size >= WS_NEED) {
        uint4* W    = (uint4*)d_ws;
        float* bias = (float*)((char*)d_ws + BIASOFF);
        kan_wb<<<288, 256, 0, stream>>>(coef, scale_base, scale_sp, mask, W, bias);
        kan_fgemm<<<256, 512, 0, stream>>>(x, W, bias, out);
    } else {
        kan_mfma<<<dim3(BATCH / 32, OUTD / 32), 256, 0, stream>>>(
            x, coef, scale_base, scale_sp, mask, out);
    }
}

// Round 12
// 18.754 us; speedup vs baseline: 1.3806x; 1.3806x over previous
//
#include <hip/hip_runtime.h>

#define BATCH 2048
#define IND   256
#define OUTD  256

typedef __attribute__((ext_vector_type(8))) short bf16x8;
typedef __attribute__((ext_vector_type(4))) float f32x4;

__device__ __forceinline__ ushort f2bf(float f) {
    uint u = __builtin_bit_cast(uint, f);
    u += 0x7fffu + ((u >> 16) & 1u);          // RNE
    return (ushort)(u >> 16);
}
__device__ __forceinline__ uint pack2(float lo, float hi) {
    return (uint)f2bf(lo) | ((uint)f2bf(hi) << 16);
}

// ---------------- ws layout ----------------
#define BIASOFF (1u << 20)                 // W: [0, 1MB)
#define FOFF    ((1u << 20) + 4096)        // F: 8MB
#define WS_NEED ((size_t)FOFF + (size_t)IND * BATCH * 16)

// features for one x value: [silu, B0..B6] (c7 folded: B7 = 1 - sum -> bias)
__device__ __forceinline__ uint4 feat_pack(float xv) {
    const float u = (xv + 1.0f) * 2.5f;
    float cif = floorf(u);
    cif = fminf(fmaxf(cif, 0.0f), 4.0f);
    const int ci = (int)cif;
    const float f = u - cif, mf = 1.0f - f;
    const float f2 = f * f, f3 = f2 * f;
    const float k6 = 1.0f / 6.0f;
    const float w0 = mf * mf * mf * k6;
    const float w1 = (3.0f * f3 - 6.0f * f2 + 4.0f) * k6;
    const float w3 = f3 * k6;
    const float w2 = 1.0f - w0 - w1 - w3;
    const float sg = __fdividef(xv, 1.0f + __expf(-xv));
    const float B0 = (ci == 0) ? w0 : 0.f;
    const float B1 = (ci == 1) ? w0 : (ci == 0) ? w1 : 0.f;
    const float B2 = (ci == 2) ? w0 : (ci == 1) ? w1 : (ci == 0) ? w2 : 0.f;
    const float B3 = (ci == 3) ? w0 : (ci == 2) ? w1 : (ci == 1) ? w2 : (ci == 0) ? w3 : 0.f;
    const float B4 = (ci == 4) ? w0 : (ci == 3) ? w1 : (ci == 2) ? w2 : (ci == 1) ? w3 : 0.f;
    const float B5 = (ci == 4) ? w1 : (ci == 3) ? w2 : (ci == 2) ? w3 : 0.f;
    const float B6 = (ci == 4) ? w2 : (ci == 3) ? w3 : 0.f;
    uint4 v;
    v.x = pack2(sg, B0); v.y = pack2(B1, B2);
    v.z = pack2(B3, B4); v.w = pack2(B5, B6);
    return v;
}

// ============ kernel 1: prep (R8 verbatim — proven) ============
__global__ __launch_bounds__(256) void kan_prep(
    const float* __restrict__ x, const float* __restrict__ coef,
    const float* __restrict__ sb, const float* __restrict__ ss,
    const float* __restrict__ mask,
    uint4* __restrict__ W, float* __restrict__ bias, uint4* __restrict__ F)
{
    const int bid = blockIdx.x, tid = threadIdx.x;
    __shared__ float xt[4 * 260];
    __shared__ float part[32][8];

    const int b0 = (bid & 7) * 256 + (bid >> 3) * 4;
    {
        const int row = tid >> 6, c4 = (tid & 63) * 4;
        const float4 v = *reinterpret_cast<const float4*>(
            x + (size_t)(b0 + row) * IND + c4);
        xt[row * 260 + c4 + 0] = v.x;
        xt[row * 260 + c4 + 1] = v.y;
        xt[row * 260 + c4 + 2] = v.z;
        xt[row * 260 + c4 + 3] = v.w;
    }

    if (tid < 128) {
        const int i = bid >> 1, o = (bid & 1) * 128 + tid;
        const int io = i * OUTD + o;
        const float m = mask[io], b = sb[io], sp = ss[io];
        const float4* cp = reinterpret_cast<const float4*>(coef + (size_t)io * 8);
        const float4 c0 = cp[0], c1 = cp[1];
        const float wb = m * b, wsp = m * sp;
        const float c7 = c1.w;
        uint4 w;
        w.x = pack2(wb,                wsp * (c0.x - c7));
        w.y = pack2(wsp * (c0.y - c7), wsp * (c0.z - c7));
        w.z = pack2(wsp * (c0.w - c7), wsp * (c1.x - c7));
        w.w = pack2(wsp * (c1.y - c7), wsp * (c1.z - c7));
        W[io] = w;
    }
    __syncthreads();

#pragma unroll
    for (int p = 0; p < 4; ++p) {
        const int q = p * 256 + tid;
        const int i = q >> 2, b = q & 3;
        F[(size_t)i * BATCH + b0 + b] = feat_pack(xt[b * 260 + i]);
    }

    if (bid >= 480) {
        const int o0 = (bid - 480) * 8;
        const int ol = tid & 7, ig = tid >> 3;
        float s = 0.f;
#pragma unroll
        for (int ii = 0; ii < 8; ++ii) {
            const int i = ig * 8 + ii;
            const int io = i * OUTD + o0 + ol;
            s += mask[io] * ss[io] * coef[(size_t)io * 8 + 7];
        }
        part[ig][ol] = s;
        __syncthreads();
        if (tid < 8) {
            float acc = 0.f;
#pragma unroll
            for (int g2 = 0; g2 < 32; ++g2) acc += part[g2][tid];
            bias[o0 + tid] = acc;
        }
    }
}

// ============ kernel 2: register-direct GEMM, 2 blocks/CU (occupancy A/B vs R8) ============
// 512 blocks x 512 threads (2 blocks/CU = 4 waves/SIMD). Block tile 32M x 32N.
// xcd = bid&7, rest = bid>>3: m-tile = xcd*8 + (rest>>3) (XCD-local F slice),
// o-tile = rest&7 (1MB W replicates into each XCD L2). 8 waves = kq(4-way K-split)
// x mh(2 M-halves). Wave tile 16x32 = 1x2 frags; per t-step 3 loads + 2 MFMA,
// depth-4 rotation, 16 steps, no in-loop barriers (R8 structure).
__global__ __launch_bounds__(512, 4) void kan_gemm(
    const uint4* __restrict__ F, const uint4* __restrict__ W,
    const float* __restrict__ bias, float* __restrict__ out)
{
    const int tid  = threadIdx.x;
    const int lane = tid & 63, wid = tid >> 6;
    const int mh = wid & 1, kq = wid >> 1;            // kq 0..3
    const int r = lane & 15, g = lane >> 4;
    const int bid = blockIdx.x;
    const int xcd = bid & 7, rest = bid >> 3;
    const int b0 = (xcd * 8 + (rest >> 3)) * 32;      // XCD-local m-tile
    const int o0 = (rest & 7) * 32;

    const uint4* pA = F + (size_t)(kq * 64 + g) * BATCH + b0 + mh * 16 + r;
    const uint4* pB = W + (size_t)(kq * 64 + g) * OUTD + o0 + r;

    f32x4 acc[2] = {};
    bf16x8 a_0, b0_0, b1_0;
    bf16x8 a_1, b0_1, b1_1;
    bf16x8 a_2, b0_2, b1_2;
    bf16x8 a_3, b0_3, b1_3;

#define LDS_(s, t)                                                                     \
    {                                                                                  \
        a_##s  = *reinterpret_cast<const bf16x8*>(pA + (size_t)(4 * (t)) * BATCH);     \
        b0_##s = *reinterpret_cast<const bf16x8*>(pB + (size_t)(4 * (t)) * OUTD);      \
        b1_##s = *reinterpret_cast<const bf16x8*>(pB + (size_t)(4 * (t)) * OUTD + 16); \
    }
#define MM_(s)                                                                         \
    {                                                                                  \
        acc[0] = __builtin_amdgcn_mfma_f32_16x16x32_bf16(a_##s, b0_##s, acc[0], 0, 0, 0); \
        acc[1] = __builtin_amdgcn_mfma_f32_16x16x32_bf16(a_##s, b1_##s, acc[1], 0, 0, 0); \
    }

    LDS_(0, 0)  LDS_(1, 1)  LDS_(2, 2)  LDS_(3, 3)
    MM_(0) LDS_(0, 4)   MM_(1) LDS_(1, 5)   MM_(2) LDS_(2, 6)   MM_(3) LDS_(3, 7)
    MM_(0) LDS_(0, 8)   MM_(1) LDS_(1, 9)   MM_(2) LDS_(2, 10)  MM_(3) LDS_(3, 11)
    MM_(0) LDS_(0, 12)  MM_(1) LDS_(1, 13)  MM_(2) LDS_(2, 14)  MM_(3) LDS_(3, 15)
    MM_(0) MM_(1) MM_(2) MM_(3)
#undef LDS_
#undef MM_

    // ---- epilogue: 4-way kq-reduce per mh via LDS, add bias, store ----
    __shared__ float red[2][3][512];   // 12 KB
    if (kq > 0) {
        float* dst = &red[mh][kq - 1][0];
#pragma unroll
        for (int nf = 0; nf < 2; ++nf)
            *reinterpret_cast<f32x4*>(dst + nf * 256 + lane * 4) = acc[nf];
    }
    __syncthreads();
    if (kq == 0) {
#pragma unroll
        for (int nf = 0; nf < 2; ++nf) {
            f32x4 s = acc[nf];
            const int sl = nf * 256 + lane * 4;
#pragma unroll
            for (int kk = 0; kk < 3; ++kk) {
                const f32x4 v = *reinterpret_cast<const f32x4*>(&red[mh][kk][0] + sl);
                s.x += v.x; s.y += v.y; s.z += v.z; s.w += v.w;
            }
            const int col  = o0 + nf * 16 + r;
            const int row0 = b0 + mh * 16 + g * 4;
            const float bv = bias[col];
#pragma unroll
            for (int e = 0; e < 4; ++e)
                out[(size_t)(row0 + e) * OUTD + col] = s[e] + bv;
        }
    }
}

// ============ fallback (used only if ws too small) ============
#define KPI  16
#define IPC  8
#define KC   (IPC * KPI)

__global__ __launch_bounds__(256, 2) void kan_mfma(
    const float* __restrict__ x, const float* __restrict__ coef,
    const float* __restrict__ scale_base, const float* __restrict__ scale_sp,
    const float* __restrict__ mask, float* __restrict__ out)
{
    const int tid = threadIdx.x;
    const int b0 = blockIdx.x * 32, o0 = blockIdx.y * 32;
    __shared__ uint Fa[32 * KC / 2];
    __shared__ uint Wt2[32 * KC / 2];
    for (int j = tid; j < 32 * KC / 2; j += 256) { Fa[j] = 0u; Wt2[j] = 0u; }
    const int lane = tid & 63, wid = tid >> 6;
    const int wmv = (wid >> 1) * 16, wnv = (wid & 1) * 16;
    f32x4 acc = {0.f, 0.f, 0.f, 0.f};
    const int fb = tid & 31, il = tid >> 5;
    for (int ic = 0; ic < IND / IPC; ++ic) {
        const int i = ic * IPC + il;
        __syncthreads();
        {
            const uint4 fp = feat_pack(x[(b0 + fb) * IND + i]);
            const int base = fb * (KC / 2) + il * (KPI / 2);
            const int sw = (fb & 7) << 2;
            Fa[(base + 0) ^ sw] = fp.x; Fa[(base + 1) ^ sw] = fp.y;
            Fa[(base + 2) ^ sw] = fp.z; Fa[(base + 3) ^ sw] = fp.w;
            ((ushort*)Fa)[2 * ((base + 4) ^ sw)] = 0;
        }
        {
            const int io = i * OUTD + o0 + fb;
            const float m = mask[io];
            const float wb = scale_base[io] * m, wsv = scale_sp[io] * m;
            const float4* cp = reinterpret_cast<const float4*>(coef + (size_t)io * 8);
            const float4 c0 = cp[0], c1 = cp[1];
            const float c7 = c1.w;
            const int base = fb * (KC / 2) + il * (KPI / 2);
            const int sw = (fb & 7) << 2;
            Wt2[(base + 0) ^ sw] = pack2(wb, wsv * (c0.x - c7));
            Wt2[(base + 1) ^ sw] = pack2(wsv * (c0.y - c7), wsv * (c0.z - c7));
            Wt2[(base + 2) ^ sw] = pack2(wsv * (c0.w - c7), wsv * (c1.x - c7));
            Wt2[(base + 3) ^ sw] = pack2(wsv * (c1.y - c7), wsv * (c1.z - c7));
            ((ushort*)Wt2)[2 * ((base + 4) ^ sw)] = 0;
        }
        __syncthreads();
        {
            const ushort* fs = (const ushort*)Fa;
            const ushort* wsd = (const ushort*)Wt2;
            const int ar = wmv + (lane & 15), br = wnv + (lane & 15);
            const int kg = (lane >> 4) * 8;
#pragma unroll
            for (int ksi = 0; ksi < 4; ++ksi) {
                const int ka = ksi * 32 + kg;
                const int ia = (ar * KC + ka) ^ ((ar & 7) << 3);
                const int ib = (br * KC + ka) ^ ((br & 7) << 3);
                bf16x8 a = *reinterpret_cast<const bf16x8*>(fs + ia);
                bf16x8 b = *reinterpret_cast<const bf16x8*>(wsd + ib);
                acc = __builtin_amdgcn_mfma_f32_16x16x32_bf16(a, b, acc, 0, 0, 0);
            }
        }
    }
    const int col = o0 + wnv + (lane & 15);
    const int row0 = b0 + wmv + ((lane >> 4) << 2);
    float bv = 0.f;
    for (int i = 0; i < IND; ++i) {
        const int io = i * OUTD + col;
        bv += mask[io] * scale_sp[io] * coef[(size_t)io * 8 + 7];
    }
#pragma unroll
    for (int rr = 0; rr < 4; ++rr)
        out[(size_t)(row0 + rr) * OUTD + col] = acc[rr] + bv;
}

extern "C" void kernel_launch(void* const* d_in, const int* in_sizes, int n_in,
                              void* d_out, int out_size, void* d_ws, size_t ws_size,
                              hipStream_t stream) {
    const float* x          = (const float*)d_in[0];
    const float* coef       = (const float*)d_in[2];
    const float* scale_base = (const float*)d_in[3];
    const float* scale_sp   = (const float*)d_in[4];
    const float* mask       = (const float*)d_in[5];
    float* out = (float*)d_out;

    if (ws_size >= WS_NEED) {
        uint4* W    = (uint4*)d_ws;
        float* bias = (float*)((char*)d_ws + BIASOFF);
        uint4* F    = (uint4*)((char*)d_ws + FOFF);
        kan_prep<<<512, 256, 0, stream>>>(x, coef, scale_base, scale_sp, mask, W, bias, F);
        kan_gemm<<<512, 512, 0, stream>>>(F, W, bias, out);
    } else {
        kan_mfma<<<dim3(BATCH / 32, OUTD / 32), 256, 0, stream>>>(
            x, coef, scale_base, scale_sp, mask, out);
    }
}